// Round 8
// baseline (207.378 us; speedup 1.0000x reference)
//
#include <hip/hip_runtime.h>
#include <hip/hip_bf16.h>
#include <hip/hip_cooperative_groups.h>

namespace cg = cooperative_groups;

typedef __attribute__((ext_vector_type(8))) short short8;   // 8 bf16 (4 VGPRs)
typedef __attribute__((ext_vector_type(4))) float float4v;  // 4 fp32 acc

// z is pre-scaled by sqrt(2*log2(e)), so MFMA dot = 2*log2(e)*cos and
// exp(2*cos) = exp2(dot) directly.
#define ZSCALE 1.6986436f

#if __has_builtin(__builtin_amdgcn_exp2f)
#define VEXP2(x) __builtin_amdgcn_exp2f(x)   /* raw v_exp_f32; args in [-2.95,2.95] */
#else
#define VEXP2(x) exp2f(x)
#endif

__device__ __forceinline__ float bf16lo(unsigned int u){ return __uint_as_float((u & 0xFFFFu) << 16); }
__device__ __forceinline__ float bf16hi(unsigned int u){ return __uint_as_float(u & 0xFFFF0000u); }

__device__ __forceinline__ unsigned int pack_bf16(float x, float y){
    __hip_bfloat16 h0 = __float2bfloat16(x);
    __hip_bfloat16 h1 = __float2bfloat16(y);
    unsigned short b0, b1;
    __builtin_memcpy(&b0, &h0, 2);
    __builtin_memcpy(&b1, &h1, 2);
    return (unsigned int)b0 | ((unsigned int)b1 << 16);
}

// ---------- shared device helpers (used by fused kernel and fallback kernels) ----------

// Phase A body: one group per wave. Normalize rows (fp32 norm clamp 1e-8), scale
// ZSCALE, round bf16, store packed; zero t rows; pos/self from fp32 dots of the
// SAME bf16 z (consistent with MFMA sums). Fast path c==4, generic fallback.
__device__ __forceinline__ void prep_group(const float* __restrict__ f,
                                           const int* __restrict__ nc,
                                           unsigned int* __restrict__ zb,
                                           float* __restrict__ t,
                                           float* __restrict__ possum,
                                           float* __restrict__ selfs,
                                           int g, int lane){
    int st = 0;
    {
        int i = lane;
        for (; i + 192 < g; i += 256)
            st += nc[i] + nc[i + 64] + nc[i + 128] + nc[i + 192];
        for (; i < g; i += 64) st += nc[i];
    }
    #pragma unroll
    for (int m = 1; m < 64; m <<= 1) st += __shfl_xor(st, m);
    int c = nc[g];
    for (int i = lane; i < c; i += 64) t[st + i] = 0.0f;

    if (c == 4){
        float2 v[4]; float ss[4];
        #pragma unroll
        for (int a = 0; a < 4; a++){
            v[a] = ((const float2*)(f + (size_t)(st + a) * 128))[lane];
            ss[a] = v[a].x * v[a].x + v[a].y * v[a].y;
        }
        #pragma unroll
        for (int m = 1; m < 64; m <<= 1){
            ss[0] += __shfl_xor(ss[0], m);
            ss[1] += __shfl_xor(ss[1], m);
            ss[2] += __shfl_xor(ss[2], m);
            ss[3] += __shfl_xor(ss[3], m);
        }
        float zx[4], zy[4];
        #pragma unroll
        for (int a = 0; a < 4; a++){
            float scale = ZSCALE / fmaxf(sqrtf(ss[a]), 1e-8f);
            unsigned int pk = pack_bf16(v[a].x * scale, v[a].y * scale);
            zb[(st + a) * 64 + lane] = pk;
            zx[a] = bf16lo(pk); zy[a] = bf16hi(pk);
        }
        float s[10];
        s[0] = zx[0]*zx[0] + zy[0]*zy[0];
        s[1] = zx[0]*zx[1] + zy[0]*zy[1];
        s[2] = zx[0]*zx[2] + zy[0]*zy[2];
        s[3] = zx[0]*zx[3] + zy[0]*zy[3];
        s[4] = zx[1]*zx[1] + zy[1]*zy[1];
        s[5] = zx[1]*zx[2] + zy[1]*zy[2];
        s[6] = zx[1]*zx[3] + zy[1]*zy[3];
        s[7] = zx[2]*zx[2] + zy[2]*zy[2];
        s[8] = zx[2]*zx[3] + zy[2]*zy[3];
        s[9] = zx[3]*zx[3] + zy[3]*zy[3];
        #pragma unroll
        for (int m = 1; m < 64; m <<= 1)
            #pragma unroll
            for (int u = 0; u < 10; u++) s[u] += __shfl_xor(s[u], m);
        if (lane == 0){
            float E0 = exp2f(s[0]), E1 = exp2f(s[1]), E2 = exp2f(s[2]), E3 = exp2f(s[3]);
            float E4 = exp2f(s[4]), E5 = exp2f(s[5]), E6 = exp2f(s[6]), E7 = exp2f(s[7]);
            float E8 = exp2f(s[8]), E9 = exp2f(s[9]);
            possum[st + 0] = E1 + E2 + E3;  selfs[st + 0] = E0;
            possum[st + 1] = E1 + E5 + E6;  selfs[st + 1] = E4;
            possum[st + 2] = E2 + E5 + E8;  selfs[st + 2] = E7;
            possum[st + 3] = E3 + E6 + E8;  selfs[st + 3] = E9;
        }
    } else {
        for (int r = 0; r < c; r++){
            const float2* fr = (const float2*)(f + (size_t)(st + r) * 128);
            float2 vv = fr[lane];
            float ss2 = vv.x * vv.x + vv.y * vv.y;
            #pragma unroll
            for (int m = 1; m < 64; m <<= 1) ss2 += __shfl_xor(ss2, m);
            float scale = ZSCALE / fmaxf(sqrtf(ss2), 1e-8f);
            zb[(st + r) * 64 + lane] = pack_bf16(vv.x * scale, vv.y * scale);
        }
        for (int a = 0; a < c; a++){
            unsigned int ua = zb[(st + a) * 64 + lane];
            float a0 = bf16lo(ua), a1 = bf16hi(ua);
            float pacc = 0.0f;
            for (int b = 0; b < c; b++){
                unsigned int ub = zb[(st + b) * 64 + lane];
                float sdot = a0 * bf16lo(ub) + a1 * bf16hi(ub);
                #pragma unroll
                for (int m = 1; m < 64; m <<= 1) sdot += __shfl_xor(sdot, m);
                float e = exp2f(sdot);
                if (b == a){ if (lane == 0) selfs[st + a] = e; }
                else pacc += e;
            }
            if (lane == 0) possum[st + a] = pacc;
        }
    }
}

// Phase B body: one 256x256 tile per block (R5 strip structure). Wave = 64 rows x
// 256 cols as 16 strips of 16 cols. Loop-carried B-prefetch: strip s+1's 4 loads
// issue before strip s's MFMAs consume the previously loaded fragments — the
// compiler cannot sink a load across the loop back-edge, so the latency overlap
// survives. Epilogue = 1 v_exp + 1 v_add per element (raw builtin).
// Fragment: lane holds z[base+(lane&15)][ki*32 + (lane>>4)*8 .. +7]
// C layout: col = lane&15, row_local = mi*16 + quad*4 + r.
__device__ __forceinline__ void gram_tile(const unsigned short* __restrict__ z,
                                          float* __restrict__ t,
                                          int r0, int c0, int lane){
    int quad = lane >> 4, l15 = lane & 15;
    size_t lq = (size_t)l15 * 128 + quad * 8;
    const unsigned short* za = z + (size_t)r0 * 128;
    short8 af[4][4];
    #pragma unroll
    for (int mi = 0; mi < 4; mi++)
        #pragma unroll
        for (int ki = 0; ki < 4; ki++)
            af[mi][ki] = *(const short8*)&za[(size_t)(mi * 16) * 128 + lq + ki * 32];

    float ts[4][4];
    #pragma unroll
    for (int mi = 0; mi < 4; mi++)
        #pragma unroll
        for (int r = 0; r < 4; r++) ts[mi][r] = 0.0f;

    const unsigned short* zp = z + (size_t)c0 * 128 + lq;
    short8 bc[4];
    #pragma unroll
    for (int ki = 0; ki < 4; ki++) bc[ki] = *(const short8*)(zp + ki * 32);

    #pragma unroll 1
    for (int s = 0; s < 16; s++){
        // prefetch next strip (wraps to strip 0 on the last iter — harmless)
        const unsigned short* zn = zp + (size_t)((s + 1) & 15) * 16 * 128;
        short8 bn[4];
        #pragma unroll
        for (int ki = 0; ki < 4; ki++) bn[ki] = *(const short8*)(zn + ki * 32);

        float4v acc[4];
        #pragma unroll
        for (int mi = 0; mi < 4; mi++) acc[mi] = (float4v){0.0f, 0.0f, 0.0f, 0.0f};
        #pragma unroll
        for (int ki = 0; ki < 4; ki++)
            #pragma unroll
            for (int mi = 0; mi < 4; mi++)
                acc[mi] = __builtin_amdgcn_mfma_f32_16x16x32_bf16(af[mi][ki], bc[ki], acc[mi], 0, 0, 0);
        #pragma unroll
        for (int mi = 0; mi < 4; mi++)
            #pragma unroll
            for (int r = 0; r < 4; r++)
                ts[mi][r] += VEXP2(acc[mi][r]);
        #pragma unroll
        for (int ki = 0; ki < 4; ki++) bc[ki] = bn[ki];
    }

    #pragma unroll
    for (int mi = 0; mi < 4; mi++)
        #pragma unroll
        for (int r = 0; r < 4; r++){
            float v = ts[mi][r];
            v += __shfl_xor(v, 1);
            v += __shfl_xor(v, 2);
            v += __shfl_xor(v, 4);
            v += __shfl_xor(v, 8);
            if (l15 == 0) atomicAdd(&t[r0 + mi * 16 + quad * 4 + r], v);
        }
}

// ---------- fused cooperative kernel ----------
__global__ __launch_bounds__(256) void k_fused(const float* __restrict__ f,
                                               const int* __restrict__ nc,
                                               unsigned int* __restrict__ zb,
                                               float* __restrict__ t,
                                               float* __restrict__ possum,
                                               float* __restrict__ selfs,
                                               float* __restrict__ out,
                                               int N, int G){
    cg::grid_group grid = cg::this_grid();
    int tid = threadIdx.x, lane = tid & 63, w = tid >> 6;
    int nwaves = gridDim.x * 4;
    int gw = blockIdx.x * 4 + w;

    if (gw == 0 && lane == 0) out[0] = 0.0f;
    for (int g = gw; g < G; g += nwaves)
        prep_group(f, nc, zb, t, possum, selfs, g, lane);

    grid.sync();

    const unsigned short* z = (const unsigned short*)zb;
    int nbx = N >> 8;
    int ntiles = nbx * nbx;
    for (int tile = blockIdx.x; tile < ntiles; tile += gridDim.x){
        int bx = tile % nbx, by = tile / nbx;
        gram_tile(z, t, bx * 256 + w * 64, by * 256, lane);
    }

    grid.sync();

    if (blockIdx.x * 256 < N){
        float s = 0.0f;
        for (int r = blockIdx.x * 256 + tid; r < N; r += gridDim.x * 256){
            float p = possum[r];
            float nn = t[r] - p - selfs[r];
            s += logf(nn) - logf(p);
        }
        #pragma unroll
        for (int m = 1; m < 64; m <<= 1) s += __shfl_xor(s, m);
        __shared__ float red[4];
        if ((tid & 63) == 0) red[tid >> 6] = s;
        __syncthreads();
        if (tid == 0) atomicAdd(out, (red[0] + red[1] + red[2] + red[3]) / (float)N);
    }
}

// ---------- fallback (non-cooperative) kernels, in case coop launch is rejected ----------
__global__ void k_prep(const float* __restrict__ f, const int* __restrict__ nc,
                       unsigned int* __restrict__ zb, float* __restrict__ t,
                       float* __restrict__ possum, float* __restrict__ selfs,
                       float* __restrict__ out, int G){
    int lane = threadIdx.x & 63;
    int g = blockIdx.x * 4 + (threadIdx.x >> 6);
    if (g == 0 && lane == 0) out[0] = 0.0f;
    if (g >= G) return;
    prep_group(f, nc, zb, t, possum, selfs, g, lane);
}

__global__ __launch_bounds__(256) void k_gram(const unsigned short* __restrict__ z,
                                              float* __restrict__ t, int N){
    int lane = threadIdx.x & 63, w = threadIdx.x >> 6;
    gram_tile(z, t, blockIdx.x * 256 + w * 64, blockIdx.y * 256, lane);
}

__global__ void k_final(const float* __restrict__ t, const float* __restrict__ possum,
                        const float* __restrict__ selfs, float* __restrict__ out, int N){
    int tid = threadIdx.x;
    int gid = blockIdx.x * 256 + tid;
    float s = 0.0f;
    if (gid < N){
        float p = possum[gid];
        float nn = t[gid] - p - selfs[gid];
        s = logf(nn) - logf(p);
    }
    #pragma unroll
    for (int m = 1; m < 64; m <<= 1) s += __shfl_xor(s, m);
    __shared__ float red[4];
    if ((tid & 63) == 0) red[tid >> 6] = s;
    __syncthreads();
    if (tid == 0) atomicAdd(out, (red[0] + red[1] + red[2] + red[3]) / (float)N);
}

extern "C" void kernel_launch(void* const* d_in, const int* in_sizes, int n_in,
                              void* d_out, int out_size, void* d_ws, size_t ws_size,
                              hipStream_t stream){
    const float* f  = (const float*)d_in[0];
    const int*   nc = (const int*)d_in[1];
    int N = in_sizes[0] / 128;   // 8192
    int G = in_sizes[1];         // 2048

    unsigned int* zb = (unsigned int*)d_ws;                       // N*256 B bf16 z (pre-scaled)
    float* t     = (float*)((char*)d_ws + (size_t)N * 256);       // N fp32
    float* pos   = t + N;
    float* selfs = pos + N;
    float* out   = (float*)d_out;

    // One cooperative launch: prep -> grid.sync -> gram -> grid.sync -> finalize.
    // 512 blocks x 256 thr = 2 blocks/CU — co-resident at any VGPR count <= 256.
    void* args[] = {(void*)&f, (void*)&nc, (void*)&zb, (void*)&t,
                    (void*)&pos, (void*)&selfs, (void*)&out, (void*)&N, (void*)&G};
    hipError_t e = hipLaunchCooperativeKernel((const void*)k_fused, dim3(512), dim3(256),
                                              args, 0, stream);
    if (e != hipSuccess){
        // fallback: 3-kernel pipeline (proven correct R5-R7 structure)
        k_prep<<<(G + 3) / 4, 256, 0, stream>>>(f, nc, zb, t, pos, selfs, out, G);
        dim3 grid(N / 256, N / 256);
        k_gram<<<grid, 256, 0, stream>>>((const unsigned short*)zb, t, N);
        k_final<<<(N + 255) / 256, 256, 0, stream>>>(t, pos, selfs, out, N);
    }
}

// Round 9
// 159.458 us; speedup vs baseline: 1.3005x; 1.3005x over previous
//
#include <hip/hip_runtime.h>
#include <hip/hip_bf16.h>

typedef __attribute__((ext_vector_type(8))) short short8;   // 8 bf16 (4 VGPRs)
typedef __attribute__((ext_vector_type(4))) float float4v;  // 4 fp32 acc

// z is pre-scaled by sqrt(2*log2(e)), so MFMA dot = 2*log2(e)*cos and
// exp(2*cos) = exp2(dot) directly — no multiply in the epilogue.
#define ZSCALE 1.6986436f

#if __has_builtin(__builtin_amdgcn_exp2f)
#define VEXP2(x) __builtin_amdgcn_exp2f(x)   /* raw v_exp_f32; args in [-2.95,2.95] */
#else
#define VEXP2(x) exp2f(x)
#endif

__device__ __forceinline__ float bf16lo(unsigned int u){ return __uint_as_float((u & 0xFFFFu) << 16); }
__device__ __forceinline__ float bf16hi(unsigned int u){ return __uint_as_float(u & 0xFFFF0000u); }

__device__ __forceinline__ unsigned int pack_bf16(float x, float y){
    __hip_bfloat16 h0 = __float2bfloat16(x);
    __hip_bfloat16 h1 = __float2bfloat16(y);
    unsigned short b0, b1;
    __builtin_memcpy(&b0, &h0, 2);
    __builtin_memcpy(&b1, &h1, 2);
    return (unsigned int)b0 | ((unsigned int)b1 << 16);
}

// K1 (prep): one wave per group, 4 groups per block.
// Normalize rows (fp32 norm clamp 1e-8), scale ZSCALE, round bf16, store packed;
// zero t rows; pos/self from fp32 dots of the SAME bf16 z. Fast path c==4.
// Group-0 wave also zeroes out[0] and the per-slab counters.
__global__ void k_prep(const float* __restrict__ f, const int* __restrict__ nc,
                       unsigned int* __restrict__ zb, float* __restrict__ t,
                       float* __restrict__ possum, float* __restrict__ selfs,
                       float* __restrict__ out, int* __restrict__ cnt,
                       int G, int nbx){
    int lane = threadIdx.x & 63;
    int g = blockIdx.x * 4 + (threadIdx.x >> 6);
    if (g >= G) return;
    if (g == 0){
        if (lane == 0) out[0] = 0.0f;
        for (int i = lane; i < nbx; i += 64) cnt[i] = 0;
    }
    int st = 0;
    {
        int i = lane;
        for (; i + 192 < g; i += 256)
            st += nc[i] + nc[i + 64] + nc[i + 128] + nc[i + 192];
        for (; i < g; i += 64) st += nc[i];
    }
    #pragma unroll
    for (int m = 1; m < 64; m <<= 1) st += __shfl_xor(st, m);
    int c = nc[g];
    for (int i = lane; i < c; i += 64) t[st + i] = 0.0f;

    if (c == 4){
        float2 v[4]; float ss[4];
        #pragma unroll
        for (int a = 0; a < 4; a++){
            v[a] = ((const float2*)(f + (size_t)(st + a) * 128))[lane];
            ss[a] = v[a].x * v[a].x + v[a].y * v[a].y;
        }
        #pragma unroll
        for (int m = 1; m < 64; m <<= 1){
            ss[0] += __shfl_xor(ss[0], m);
            ss[1] += __shfl_xor(ss[1], m);
            ss[2] += __shfl_xor(ss[2], m);
            ss[3] += __shfl_xor(ss[3], m);
        }
        float zx[4], zy[4];
        #pragma unroll
        for (int a = 0; a < 4; a++){
            float scale = ZSCALE / fmaxf(sqrtf(ss[a]), 1e-8f);
            unsigned int pk = pack_bf16(v[a].x * scale, v[a].y * scale);
            zb[(st + a) * 64 + lane] = pk;
            zx[a] = bf16lo(pk); zy[a] = bf16hi(pk);   // the SAME values k_gram sees
        }
        float s[10];
        s[0] = zx[0]*zx[0] + zy[0]*zy[0];
        s[1] = zx[0]*zx[1] + zy[0]*zy[1];
        s[2] = zx[0]*zx[2] + zy[0]*zy[2];
        s[3] = zx[0]*zx[3] + zy[0]*zy[3];
        s[4] = zx[1]*zx[1] + zy[1]*zy[1];
        s[5] = zx[1]*zx[2] + zy[1]*zy[2];
        s[6] = zx[1]*zx[3] + zy[1]*zy[3];
        s[7] = zx[2]*zx[2] + zy[2]*zy[2];
        s[8] = zx[2]*zx[3] + zy[2]*zy[3];
        s[9] = zx[3]*zx[3] + zy[3]*zy[3];
        #pragma unroll
        for (int m = 1; m < 64; m <<= 1)
            #pragma unroll
            for (int u = 0; u < 10; u++) s[u] += __shfl_xor(s[u], m);
        if (lane == 0){
            float E0 = exp2f(s[0]), E1 = exp2f(s[1]), E2 = exp2f(s[2]), E3 = exp2f(s[3]);
            float E4 = exp2f(s[4]), E5 = exp2f(s[5]), E6 = exp2f(s[6]), E7 = exp2f(s[7]);
            float E8 = exp2f(s[8]), E9 = exp2f(s[9]);
            possum[st + 0] = E1 + E2 + E3;  selfs[st + 0] = E0;
            possum[st + 1] = E1 + E5 + E6;  selfs[st + 1] = E4;
            possum[st + 2] = E2 + E5 + E8;  selfs[st + 2] = E7;
            possum[st + 3] = E3 + E6 + E8;  selfs[st + 3] = E9;
        }
    } else {
        for (int r = 0; r < c; r++){
            const float2* fr = (const float2*)(f + (size_t)(st + r) * 128);
            float2 vv = fr[lane];
            float ss2 = vv.x * vv.x + vv.y * vv.y;
            #pragma unroll
            for (int m = 1; m < 64; m <<= 1) ss2 += __shfl_xor(ss2, m);
            float scale = ZSCALE / fmaxf(sqrtf(ss2), 1e-8f);
            zb[(st + r) * 64 + lane] = pack_bf16(vv.x * scale, vv.y * scale);
        }
        for (int a = 0; a < c; a++){
            unsigned int ua = zb[(st + a) * 64 + lane];
            float a0 = bf16lo(ua), a1 = bf16hi(ua);
            float pacc = 0.0f;
            for (int b = 0; b < c; b++){
                unsigned int ub = zb[(st + b) * 64 + lane];
                float sdot = a0 * bf16lo(ub) + a1 * bf16hi(ub);
                #pragma unroll
                for (int m = 1; m < 64; m <<= 1) sdot += __shfl_xor(sdot, m);
                float e = exp2f(sdot);
                if (b == a){ if (lane == 0) selfs[st + a] = e; }
                else pacc += e;
            }
            if (lane == 0) possum[st + a] = pacc;
        }
    }
}

// K2: Gram row-sums (exact R5 strip structure — best measured) + fused finalize.
// Grid (nbx, nbx); block = 4 independent waves; wave = 64 rows x 256 cols as 16
// strips of 16 cols; epilogue = 1 v_exp + 1 v_add per element (VEXP2).
// After a block's atomics: threadfence + per-row-slab counter; the 32nd (last)
// finisher of slab bx computes the 256 rows' log(neg)-log(pos) (coherent t reads
// via atomicAdd(+0)) and atomicAdds the partial loss into out. Device-scope
// atomics only — no dispatch-order or co-residency assumptions (G16-safe).
// Fragment: lane holds z[base+(lane&15)][ki*32 + (lane>>4)*8 .. +7]
// C layout: col = lane&15, row_local = mi*16 + quad*4 + r.
__global__ __launch_bounds__(256) void k_gram(const unsigned short* __restrict__ z,
                                              float* __restrict__ t,
                                              const float* __restrict__ possum,
                                              const float* __restrict__ selfs,
                                              int* __restrict__ cnt,
                                              float* __restrict__ out, int N){
    int tid  = threadIdx.x;
    int lane = tid & 63, w = tid >> 6;
    int quad = lane >> 4, l15 = lane & 15;
    int bx = blockIdx.x, nbx = gridDim.x;
    int r0 = bx * 256 + w * 64;
    int c0 = blockIdx.y * 256;
    size_t lq = (size_t)l15 * 128 + quad * 8;

    const unsigned short* za = z + (size_t)r0 * 128;
    short8 af[4][4];
    #pragma unroll
    for (int mi = 0; mi < 4; mi++)
        #pragma unroll
        for (int ki = 0; ki < 4; ki++)
            af[mi][ki] = *(const short8*)&za[(size_t)(mi * 16) * 128 + lq + ki * 32];

    float ts[4][4];
    #pragma unroll
    for (int mi = 0; mi < 4; mi++)
        #pragma unroll
        for (int r = 0; r < 4; r++) ts[mi][r] = 0.0f;

    const unsigned short* zp = z + (size_t)c0 * 128 + lq;
    #pragma unroll 1
    for (int s = 0; s < 16; s++){
        short8 b0 = *(const short8*)(zp);
        short8 b1 = *(const short8*)(zp + 32);
        short8 b2 = *(const short8*)(zp + 64);
        short8 b3 = *(const short8*)(zp + 96);
        float4v acc[4];
        #pragma unroll
        for (int mi = 0; mi < 4; mi++) acc[mi] = (float4v){0.0f, 0.0f, 0.0f, 0.0f};
        #pragma unroll
        for (int mi = 0; mi < 4; mi++)
            acc[mi] = __builtin_amdgcn_mfma_f32_16x16x32_bf16(af[mi][0], b0, acc[mi], 0, 0, 0);
        #pragma unroll
        for (int mi = 0; mi < 4; mi++)
            acc[mi] = __builtin_amdgcn_mfma_f32_16x16x32_bf16(af[mi][1], b1, acc[mi], 0, 0, 0);
        #pragma unroll
        for (int mi = 0; mi < 4; mi++)
            acc[mi] = __builtin_amdgcn_mfma_f32_16x16x32_bf16(af[mi][2], b2, acc[mi], 0, 0, 0);
        #pragma unroll
        for (int mi = 0; mi < 4; mi++)
            acc[mi] = __builtin_amdgcn_mfma_f32_16x16x32_bf16(af[mi][3], b3, acc[mi], 0, 0, 0);
        #pragma unroll
        for (int mi = 0; mi < 4; mi++)
            #pragma unroll
            for (int r = 0; r < 4; r++)
                ts[mi][r] += VEXP2(acc[mi][r]);
        zp += 16 * 128;   // next 16-col strip
    }

    // reduce across the 16 column-lanes (same quad), one atomic per row
    #pragma unroll
    for (int mi = 0; mi < 4; mi++)
        #pragma unroll
        for (int r = 0; r < 4; r++){
            float v = ts[mi][r];
            v += __shfl_xor(v, 1);
            v += __shfl_xor(v, 2);
            v += __shfl_xor(v, 4);
            v += __shfl_xor(v, 8);
            if (l15 == 0) atomicAdd(&t[r0 + mi * 16 + quad * 4 + r], v);
        }

    // ---- fused finalize: last block to finish row-slab bx computes its loss part ----
    __threadfence();            // release our t contributions (device scope)
    __syncthreads();            // all 4 waves' atomics issued before counting
    __shared__ int lastflag;
    if (tid == 0) lastflag = (atomicAdd(&cnt[bx], 1) == nbx - 1);
    __syncthreads();
    if (lastflag){
        int r = bx * 256 + tid;     // 256 rows per slab, one per thread
        float s = 0.0f;
        if (r < N){
            float tv = atomicAdd(&t[r], 0.0f);   // coherent read of completed row sum
            float p  = possum[r];
            float nn = tv - p - selfs[r];
            s = logf(nn) - logf(p);
        }
        #pragma unroll
        for (int m = 1; m < 64; m <<= 1) s += __shfl_xor(s, m);
        __shared__ float red[4];
        if ((tid & 63) == 0) red[tid >> 6] = s;
        __syncthreads();
        if (tid == 0) atomicAdd(out, (red[0] + red[1] + red[2] + red[3]) / (float)N);
    }
}

extern "C" void kernel_launch(void* const* d_in, const int* in_sizes, int n_in,
                              void* d_out, int out_size, void* d_ws, size_t ws_size,
                              hipStream_t stream){
    const float* f  = (const float*)d_in[0];
    const int*   nc = (const int*)d_in[1];
    int N = in_sizes[0] / 128;   // 8192
    int G = in_sizes[1];         // 2048
    int nbx = N / 256;           // 32 row-slabs

    unsigned int* zb = (unsigned int*)d_ws;                       // N*256 B bf16 z (pre-scaled)
    float* t     = (float*)((char*)d_ws + (size_t)N * 256);       // N fp32
    float* pos   = t + N;
    float* selfs = pos + N;
    int*   cnt   = (int*)(selfs + N);                             // nbx ints
    float* out   = (float*)d_out;

    k_prep<<<(G + 3) / 4, 256, 0, stream>>>(f, nc, zb, t, pos, selfs, out, cnt, G, nbx);
    dim3 grid(nbx, nbx);
    k_gram<<<grid, 256, 0, stream>>>((const unsigned short*)zb, t, pos, selfs, cnt, out, N);
}

// Round 10
// 110.738 us; speedup vs baseline: 1.8727x; 1.4400x over previous
//
#include <hip/hip_runtime.h>
#include <hip/hip_bf16.h>

typedef __attribute__((ext_vector_type(8))) short short8;   // 8 bf16 (4 VGPRs)
typedef __attribute__((ext_vector_type(4))) float float4v;  // 4 fp32 acc

// z is pre-scaled by sqrt(2*log2(e)), so MFMA dot = 2*log2(e)*cos and
// exp(2*cos) = exp2(dot) directly — no multiply in the epilogue.
#define ZSCALE 1.6986436f

#if __has_builtin(__builtin_amdgcn_exp2f)
#define VEXP2(x) __builtin_amdgcn_exp2f(x)   /* raw v_exp_f32; args in [-2.95,2.95] */
#else
#define VEXP2(x) exp2f(x)
#endif

__device__ __forceinline__ float bf16lo(unsigned int u){ return __uint_as_float((u & 0xFFFFu) << 16); }
__device__ __forceinline__ float bf16hi(unsigned int u){ return __uint_as_float(u & 0xFFFF0000u); }

__device__ __forceinline__ unsigned int pack_bf16(float x, float y){
    __hip_bfloat16 h0 = __float2bfloat16(x);
    __hip_bfloat16 h1 = __float2bfloat16(y);
    unsigned short b0, b1;
    __builtin_memcpy(&b0, &h0, 2);
    __builtin_memcpy(&b1, &h1, 2);
    return (unsigned int)b0 | ((unsigned int)b1 << 16);
}

// K1 (prep): one wave per group, 4 groups per block.
// Normalize rows (fp32 norm clamp 1e-8), scale ZSCALE, round bf16, store packed;
// zero t rows; pos/self from fp32 dots of the SAME bf16 z. Fast path c==4.
__global__ void k_prep(const float* __restrict__ f, const int* __restrict__ nc,
                       unsigned int* __restrict__ zb, float* __restrict__ t,
                       float* __restrict__ possum, float* __restrict__ selfs,
                       float* __restrict__ out, int G){
    int lane = threadIdx.x & 63;
    int g = blockIdx.x * 4 + (threadIdx.x >> 6);
    if (g >= G) return;
    if (g == 0 && lane == 0) out[0] = 0.0f;
    int st = 0;
    {
        int i = lane;
        for (; i + 192 < g; i += 256)
            st += nc[i] + nc[i + 64] + nc[i + 128] + nc[i + 192];
        for (; i < g; i += 64) st += nc[i];
    }
    #pragma unroll
    for (int m = 1; m < 64; m <<= 1) st += __shfl_xor(st, m);
    int c = nc[g];
    for (int i = lane; i < c; i += 64) t[st + i] = 0.0f;

    if (c == 4){
        float2 v[4]; float ss[4];
        #pragma unroll
        for (int a = 0; a < 4; a++){
            v[a] = ((const float2*)(f + (size_t)(st + a) * 128))[lane];
            ss[a] = v[a].x * v[a].x + v[a].y * v[a].y;
        }
        #pragma unroll
        for (int m = 1; m < 64; m <<= 1){
            ss[0] += __shfl_xor(ss[0], m);
            ss[1] += __shfl_xor(ss[1], m);
            ss[2] += __shfl_xor(ss[2], m);
            ss[3] += __shfl_xor(ss[3], m);
        }
        float zx[4], zy[4];
        #pragma unroll
        for (int a = 0; a < 4; a++){
            float scale = ZSCALE / fmaxf(sqrtf(ss[a]), 1e-8f);
            unsigned int pk = pack_bf16(v[a].x * scale, v[a].y * scale);
            zb[(st + a) * 64 + lane] = pk;
            zx[a] = bf16lo(pk); zy[a] = bf16hi(pk);   // the SAME values k_gram sees
        }
        float s[10];
        s[0] = zx[0]*zx[0] + zy[0]*zy[0];
        s[1] = zx[0]*zx[1] + zy[0]*zy[1];
        s[2] = zx[0]*zx[2] + zy[0]*zy[2];
        s[3] = zx[0]*zx[3] + zy[0]*zy[3];
        s[4] = zx[1]*zx[1] + zy[1]*zy[1];
        s[5] = zx[1]*zx[2] + zy[1]*zy[2];
        s[6] = zx[1]*zx[3] + zy[1]*zy[3];
        s[7] = zx[2]*zx[2] + zy[2]*zy[2];
        s[8] = zx[2]*zx[3] + zy[2]*zy[3];
        s[9] = zx[3]*zx[3] + zy[3]*zy[3];
        #pragma unroll
        for (int m = 1; m < 64; m <<= 1)
            #pragma unroll
            for (int u = 0; u < 10; u++) s[u] += __shfl_xor(s[u], m);
        if (lane == 0){
            float E0 = exp2f(s[0]), E1 = exp2f(s[1]), E2 = exp2f(s[2]), E3 = exp2f(s[3]);
            float E4 = exp2f(s[4]), E5 = exp2f(s[5]), E6 = exp2f(s[6]), E7 = exp2f(s[7]);
            float E8 = exp2f(s[8]), E9 = exp2f(s[9]);
            possum[st + 0] = E1 + E2 + E3;  selfs[st + 0] = E0;
            possum[st + 1] = E1 + E5 + E6;  selfs[st + 1] = E4;
            possum[st + 2] = E2 + E5 + E8;  selfs[st + 2] = E7;
            possum[st + 3] = E3 + E6 + E8;  selfs[st + 3] = E9;
        }
    } else {
        for (int r = 0; r < c; r++){
            const float2* fr = (const float2*)(f + (size_t)(st + r) * 128);
            float2 vv = fr[lane];
            float ss2 = vv.x * vv.x + vv.y * vv.y;
            #pragma unroll
            for (int m = 1; m < 64; m <<= 1) ss2 += __shfl_xor(ss2, m);
            float scale = ZSCALE / fmaxf(sqrtf(ss2), 1e-8f);
            zb[(st + r) * 64 + lane] = pack_bf16(vv.x * scale, vv.y * scale);
        }
        for (int a = 0; a < c; a++){
            unsigned int ua = zb[(st + a) * 64 + lane];
            float a0 = bf16lo(ua), a1 = bf16hi(ua);
            float pacc = 0.0f;
            for (int b = 0; b < c; b++){
                unsigned int ub = zb[(st + b) * 64 + lane];
                float sdot = a0 * bf16lo(ub) + a1 * bf16hi(ub);
                #pragma unroll
                for (int m = 1; m < 64; m <<= 1) sdot += __shfl_xor(sdot, m);
                float e = exp2f(sdot);
                if (b == a){ if (lane == 0) selfs[st + a] = e; }
                else pacc += e;
            }
            if (lane == 0) possum[st + a] = pacc;
        }
    }
}

// K2: Gram row-sums, R5 strip structure with 2x grid TLP.
// Grid (N/256 row-slabs, N/128 col-chunks) = 2048 blocks = 8192 waves
// -> 8 waves/SIMD, whole grid co-resident (8 blocks/CU at VGPR<=72).
// Wave = 64 rows x 128 cols as 8 strips of 16 cols. Epilogue = 1 v_exp + 1 v_add
// per element (VEXP2; pre-scaled z makes the dot the exp2 argument).
// Fragment: lane holds z[base+(lane&15)][ki*32 + (lane>>4)*8 .. +7]
// C layout: col = lane&15, row_local = mi*16 + quad*4 + r.
__global__ __launch_bounds__(256) void k_gram(const unsigned short* __restrict__ z,
                                              float* __restrict__ t, int N){
    int tid  = threadIdx.x;
    int lane = tid & 63, w = tid >> 6;
    int quad = lane >> 4, l15 = lane & 15;
    int r0 = blockIdx.x * 256 + w * 64;
    int c0 = blockIdx.y * 128;
    size_t lq = (size_t)l15 * 128 + quad * 8;

    const unsigned short* za = z + (size_t)r0 * 128;
    short8 af[4][4];
    #pragma unroll
    for (int mi = 0; mi < 4; mi++)
        #pragma unroll
        for (int ki = 0; ki < 4; ki++)
            af[mi][ki] = *(const short8*)&za[(size_t)(mi * 16) * 128 + lq + ki * 32];

    float ts[4][4];
    #pragma unroll
    for (int mi = 0; mi < 4; mi++)
        #pragma unroll
        for (int r = 0; r < 4; r++) ts[mi][r] = 0.0f;

    const unsigned short* zp = z + (size_t)c0 * 128 + lq;
    #pragma unroll 1
    for (int s = 0; s < 8; s++){
        short8 b0 = *(const short8*)(zp);
        short8 b1 = *(const short8*)(zp + 32);
        short8 b2 = *(const short8*)(zp + 64);
        short8 b3 = *(const short8*)(zp + 96);
        float4v acc[4];
        #pragma unroll
        for (int mi = 0; mi < 4; mi++) acc[mi] = (float4v){0.0f, 0.0f, 0.0f, 0.0f};
        #pragma unroll
        for (int mi = 0; mi < 4; mi++)
            acc[mi] = __builtin_amdgcn_mfma_f32_16x16x32_bf16(af[mi][0], b0, acc[mi], 0, 0, 0);
        #pragma unroll
        for (int mi = 0; mi < 4; mi++)
            acc[mi] = __builtin_amdgcn_mfma_f32_16x16x32_bf16(af[mi][1], b1, acc[mi], 0, 0, 0);
        #pragma unroll
        for (int mi = 0; mi < 4; mi++)
            acc[mi] = __builtin_amdgcn_mfma_f32_16x16x32_bf16(af[mi][2], b2, acc[mi], 0, 0, 0);
        #pragma unroll
        for (int mi = 0; mi < 4; mi++)
            acc[mi] = __builtin_amdgcn_mfma_f32_16x16x32_bf16(af[mi][3], b3, acc[mi], 0, 0, 0);
        #pragma unroll
        for (int mi = 0; mi < 4; mi++)
            #pragma unroll
            for (int r = 0; r < 4; r++)
                ts[mi][r] += VEXP2(acc[mi][r]);
        zp += 16 * 128;   // next 16-col strip
    }

    // reduce across the 16 column-lanes (same quad), one atomic per row
    #pragma unroll
    for (int mi = 0; mi < 4; mi++)
        #pragma unroll
        for (int r = 0; r < 4; r++){
            float v = ts[mi][r];
            v += __shfl_xor(v, 1);
            v += __shfl_xor(v, 2);
            v += __shfl_xor(v, 4);
            v += __shfl_xor(v, 8);
            if (l15 == 0) atomicAdd(&t[r0 + mi * 16 + quad * 4 + r], v);
        }
}

// K3: loss = mean over rows of log(neg) - log(pos); neg = t - pos - self.
__global__ void k_final(const float* __restrict__ t, const float* __restrict__ possum,
                        const float* __restrict__ selfs, float* __restrict__ out, int N){
    int tid = threadIdx.x;
    int gid = blockIdx.x * 256 + tid;
    float s = 0.0f;
    if (gid < N){
        float p = possum[gid];
        float nn = t[gid] - p - selfs[gid];
        s = logf(nn) - logf(p);
    }
    #pragma unroll
    for (int m = 1; m < 64; m <<= 1) s += __shfl_xor(s, m);
    __shared__ float red[4];
    if ((tid & 63) == 0) red[tid >> 6] = s;
    __syncthreads();
    if (tid == 0) atomicAdd(out, (red[0] + red[1] + red[2] + red[3]) / (float)N);
}

extern "C" void kernel_launch(void* const* d_in, const int* in_sizes, int n_in,
                              void* d_out, int out_size, void* d_ws, size_t ws_size,
                              hipStream_t stream){
    const float* f  = (const float*)d_in[0];
    const int*   nc = (const int*)d_in[1];
    int N = in_sizes[0] / 128;   // 8192
    int G = in_sizes[1];         // 2048

    unsigned int* zb = (unsigned int*)d_ws;                       // N*256 B bf16 z (pre-scaled)
    float* t     = (float*)((char*)d_ws + (size_t)N * 256);       // N fp32
    float* pos   = t + N;
    float* selfs = pos + N;
    float* out   = (float*)d_out;

    k_prep<<<(G + 3) / 4, 256, 0, stream>>>(f, nc, zb, t, pos, selfs, out, G);
    dim3 grid(N / 256, N / 128);
    k_gram<<<grid, 256, 0, stream>>>((const unsigned short*)zb, t, N);
    k_final<<<(N + 255) / 256, 256, 0, stream>>>(t, pos, selfs, out, N);
}

// Round 11
// 108.731 us; speedup vs baseline: 1.9073x; 1.0185x over previous
//
#include <hip/hip_runtime.h>
#include <hip/hip_bf16.h>

typedef __attribute__((ext_vector_type(8))) short short8;   // 8 bf16 (4 VGPRs)
typedef __attribute__((ext_vector_type(4))) float float4v;  // 4 fp32 acc

// z is pre-scaled by sqrt(2*log2(e)), so MFMA dot = 2*log2(e)*cos and
// exp(2*cos) = exp2(dot) directly — no multiply in the epilogue.
#define ZSCALE 1.6986436f

#if __has_builtin(__builtin_amdgcn_exp2f)
#define VEXP2(x) __builtin_amdgcn_exp2f(x)   /* raw v_exp_f32; args in [-2.95,2.95] */
#else
#define VEXP2(x) exp2f(x)
#endif

__device__ __forceinline__ float bf16lo(unsigned int u){ return __uint_as_float((u & 0xFFFFu) << 16); }
__device__ __forceinline__ float bf16hi(unsigned int u){ return __uint_as_float(u & 0xFFFF0000u); }

__device__ __forceinline__ unsigned int pack_bf16(float x, float y){
    __hip_bfloat16 h0 = __float2bfloat16(x);
    __hip_bfloat16 h1 = __float2bfloat16(y);
    unsigned short b0, b1;
    __builtin_memcpy(&b0, &h0, 2);
    __builtin_memcpy(&b1, &h1, 2);
    return (unsigned int)b0 | ((unsigned int)b1 << 16);
}

// K1 (prep): one wave per group, 4 groups per block.
// Normalize rows (fp32 norm clamp 1e-8), scale ZSCALE, round bf16, store packed;
// zero t rows; pos/self from fp32 dots of the SAME bf16 z. Fast path c==4.
// Group-0 wave also zeroes out[0] and the per-slab counters.
__global__ void k_prep(const float* __restrict__ f, const int* __restrict__ nc,
                       unsigned int* __restrict__ zb, float* __restrict__ t,
                       float* __restrict__ possum, float* __restrict__ selfs,
                       float* __restrict__ out, int* __restrict__ cnt,
                       int G, int nbx){
    int lane = threadIdx.x & 63;
    int g = blockIdx.x * 4 + (threadIdx.x >> 6);
    if (g >= G) return;
    if (g == 0){
        if (lane == 0) out[0] = 0.0f;
        for (int i = lane; i < nbx; i += 64) cnt[i] = 0;
    }
    int st = 0;
    {
        int i = lane;
        for (; i + 192 < g; i += 256)
            st += nc[i] + nc[i + 64] + nc[i + 128] + nc[i + 192];
        for (; i < g; i += 64) st += nc[i];
    }
    #pragma unroll
    for (int m = 1; m < 64; m <<= 1) st += __shfl_xor(st, m);
    int c = nc[g];
    for (int i = lane; i < c; i += 64) t[st + i] = 0.0f;

    if (c == 4){
        float2 v[4]; float ss[4];
        #pragma unroll
        for (int a = 0; a < 4; a++){
            v[a] = ((const float2*)(f + (size_t)(st + a) * 128))[lane];
            ss[a] = v[a].x * v[a].x + v[a].y * v[a].y;
        }
        #pragma unroll
        for (int m = 1; m < 64; m <<= 1){
            ss[0] += __shfl_xor(ss[0], m);
            ss[1] += __shfl_xor(ss[1], m);
            ss[2] += __shfl_xor(ss[2], m);
            ss[3] += __shfl_xor(ss[3], m);
        }
        float zx[4], zy[4];
        #pragma unroll
        for (int a = 0; a < 4; a++){
            float scale = ZSCALE / fmaxf(sqrtf(ss[a]), 1e-8f);
            unsigned int pk = pack_bf16(v[a].x * scale, v[a].y * scale);
            zb[(st + a) * 64 + lane] = pk;
            zx[a] = bf16lo(pk); zy[a] = bf16hi(pk);   // the SAME values k_gram sees
        }
        float s[10];
        s[0] = zx[0]*zx[0] + zy[0]*zy[0];
        s[1] = zx[0]*zx[1] + zy[0]*zy[1];
        s[2] = zx[0]*zx[2] + zy[0]*zy[2];
        s[3] = zx[0]*zx[3] + zy[0]*zy[3];
        s[4] = zx[1]*zx[1] + zy[1]*zy[1];
        s[5] = zx[1]*zx[2] + zy[1]*zy[2];
        s[6] = zx[1]*zx[3] + zy[1]*zy[3];
        s[7] = zx[2]*zx[2] + zy[2]*zy[2];
        s[8] = zx[2]*zx[3] + zy[2]*zy[3];
        s[9] = zx[3]*zx[3] + zy[3]*zy[3];
        #pragma unroll
        for (int m = 1; m < 64; m <<= 1)
            #pragma unroll
            for (int u = 0; u < 10; u++) s[u] += __shfl_xor(s[u], m);
        if (lane == 0){
            float E0 = exp2f(s[0]), E1 = exp2f(s[1]), E2 = exp2f(s[2]), E3 = exp2f(s[3]);
            float E4 = exp2f(s[4]), E5 = exp2f(s[5]), E6 = exp2f(s[6]), E7 = exp2f(s[7]);
            float E8 = exp2f(s[8]), E9 = exp2f(s[9]);
            possum[st + 0] = E1 + E2 + E3;  selfs[st + 0] = E0;
            possum[st + 1] = E1 + E5 + E6;  selfs[st + 1] = E4;
            possum[st + 2] = E2 + E5 + E8;  selfs[st + 2] = E7;
            possum[st + 3] = E3 + E6 + E8;  selfs[st + 3] = E9;
        }
    } else {
        for (int r = 0; r < c; r++){
            const float2* fr = (const float2*)(f + (size_t)(st + r) * 128);
            float2 vv = fr[lane];
            float ss2 = vv.x * vv.x + vv.y * vv.y;
            #pragma unroll
            for (int m = 1; m < 64; m <<= 1) ss2 += __shfl_xor(ss2, m);
            float scale = ZSCALE / fmaxf(sqrtf(ss2), 1e-8f);
            zb[(st + r) * 64 + lane] = pack_bf16(vv.x * scale, vv.y * scale);
        }
        for (int a = 0; a < c; a++){
            unsigned int ua = zb[(st + a) * 64 + lane];
            float a0 = bf16lo(ua), a1 = bf16hi(ua);
            float pacc = 0.0f;
            for (int b = 0; b < c; b++){
                unsigned int ub = zb[(st + b) * 64 + lane];
                float sdot = a0 * bf16lo(ub) + a1 * bf16hi(ub);
                #pragma unroll
                for (int m = 1; m < 64; m <<= 1) sdot += __shfl_xor(sdot, m);
                float e = exp2f(sdot);
                if (b == a){ if (lane == 0) selfs[st + a] = e; }
                else pacc += e;
            }
            if (lane == 0) possum[st + a] = pacc;
        }
    }
}

// K2: Gram row-sums (R5 geometry — best measured: 1024 blocks, wave = 64 rows x
// 256 cols as 16 strips) + VEXP2 epilogue + fused finalize WITHOUT threadfence.
// Ordering trick: every t-update uses the RETURNING atomicAdd form (sc0) and the
// result is consumed — the ack guarantees the RMW completed at the device
// coherence point before this thread proceeds. After __syncthreads, one lane
// bumps cnt[bx]; the 32nd (last) finisher of row-slab bx reads the slab's t via
// atomicAdd(+0.0f) (coherent read, no cache writeback) and adds its loss partial
// into out. Device-scope atomics only — no dispatch-order / co-residency /
// cross-XCD-cache assumptions (G16-safe). NO __threadfence (R9 showed it costs
// 2x wall via L2 writeback).
// Fragment: lane holds z[base+(lane&15)][ki*32 + (lane>>4)*8 .. +7]
// C layout: col = lane&15, row_local = mi*16 + quad*4 + r.
__global__ __launch_bounds__(256) void k_gram(const unsigned short* __restrict__ z,
                                              float* __restrict__ t,
                                              const float* __restrict__ possum,
                                              const float* __restrict__ selfs,
                                              int* __restrict__ cnt,
                                              float* __restrict__ out, int N){
    int tid  = threadIdx.x;
    int lane = tid & 63, w = tid >> 6;
    int quad = lane >> 4, l15 = lane & 15;
    int bx = blockIdx.x, nby = gridDim.y;
    int r0 = bx * 256 + w * 64;
    int c0 = blockIdx.y * 256;
    size_t lq = (size_t)l15 * 128 + quad * 8;

    const unsigned short* za = z + (size_t)r0 * 128;
    short8 af[4][4];
    #pragma unroll
    for (int mi = 0; mi < 4; mi++)
        #pragma unroll
        for (int ki = 0; ki < 4; ki++)
            af[mi][ki] = *(const short8*)&za[(size_t)(mi * 16) * 128 + lq + ki * 32];

    float ts[4][4];
    #pragma unroll
    for (int mi = 0; mi < 4; mi++)
        #pragma unroll
        for (int r = 0; r < 4; r++) ts[mi][r] = 0.0f;

    const unsigned short* zp = z + (size_t)c0 * 128 + lq;
    #pragma unroll 1
    for (int s = 0; s < 16; s++){
        short8 b0 = *(const short8*)(zp);
        short8 b1 = *(const short8*)(zp + 32);
        short8 b2 = *(const short8*)(zp + 64);
        short8 b3 = *(const short8*)(zp + 96);
        float4v acc[4];
        #pragma unroll
        for (int mi = 0; mi < 4; mi++) acc[mi] = (float4v){0.0f, 0.0f, 0.0f, 0.0f};
        #pragma unroll
        for (int mi = 0; mi < 4; mi++)
            acc[mi] = __builtin_amdgcn_mfma_f32_16x16x32_bf16(af[mi][0], b0, acc[mi], 0, 0, 0);
        #pragma unroll
        for (int mi = 0; mi < 4; mi++)
            acc[mi] = __builtin_amdgcn_mfma_f32_16x16x32_bf16(af[mi][1], b1, acc[mi], 0, 0, 0);
        #pragma unroll
        for (int mi = 0; mi < 4; mi++)
            acc[mi] = __builtin_amdgcn_mfma_f32_16x16x32_bf16(af[mi][2], b2, acc[mi], 0, 0, 0);
        #pragma unroll
        for (int mi = 0; mi < 4; mi++)
            acc[mi] = __builtin_amdgcn_mfma_f32_16x16x32_bf16(af[mi][3], b3, acc[mi], 0, 0, 0);
        #pragma unroll
        for (int mi = 0; mi < 4; mi++)
            #pragma unroll
            for (int r = 0; r < 4; r++)
                ts[mi][r] += VEXP2(acc[mi][r]);
        zp += 16 * 128;   // next 16-col strip
    }

    // reduce across the 16 column-lanes (same quad); returning atomics, ack consumed
    float ack = 0.0f;
    #pragma unroll
    for (int mi = 0; mi < 4; mi++)
        #pragma unroll
        for (int r = 0; r < 4; r++){
            float v = ts[mi][r];
            v += __shfl_xor(v, 1);
            v += __shfl_xor(v, 2);
            v += __shfl_xor(v, 4);
            v += __shfl_xor(v, 8);
            if (l15 == 0) ack += atomicAdd(&t[r0 + mi * 16 + quad * 4 + r], v);
        }
    // consume ack (all row sums are positive; branch never taken, but the compiler
    // must keep the returning form and wait for the acks)
    if (ack == -1.0f) out[0] = 0.0f;

    __syncthreads();   // all 4 waves' t-atomics acknowledged

    __shared__ int lastflag;
    if (tid == 0) lastflag = (atomicAdd(&cnt[bx], 1) == nby - 1);
    __syncthreads();
    if (lastflag){
        int r = bx * 256 + tid;     // 256 rows per slab, one per thread
        float s = 0.0f;
        if (r < N){
            float tv = atomicAdd(&t[r], 0.0f);   // coherent read of completed row sum
            float p  = possum[r];
            float nn = tv - p - selfs[r];
            s = logf(nn) - logf(p);
        }
        #pragma unroll
        for (int m = 1; m < 64; m <<= 1) s += __shfl_xor(s, m);
        __shared__ float red[4];
        if ((tid & 63) == 0) red[tid >> 6] = s;
        __syncthreads();
        if (tid == 0) atomicAdd(out, (red[0] + red[1] + red[2] + red[3]) / (float)N);
    }
}

extern "C" void kernel_launch(void* const* d_in, const int* in_sizes, int n_in,
                              void* d_out, int out_size, void* d_ws, size_t ws_size,
                              hipStream_t stream){
    const float* f  = (const float*)d_in[0];
    const int*   nc = (const int*)d_in[1];
    int N = in_sizes[0] / 128;   // 8192
    int G = in_sizes[1];         // 2048
    int nbx = N / 256;           // 32 row-slabs

    unsigned int* zb = (unsigned int*)d_ws;                       // N*256 B bf16 z (pre-scaled)
    float* t     = (float*)((char*)d_ws + (size_t)N * 256);       // N fp32
    float* pos   = t + N;
    float* selfs = pos + N;
    int*   cnt   = (int*)(selfs + N);                             // nbx ints
    float* out   = (float*)d_out;

    k_prep<<<(G + 3) / 4, 256, 0, stream>>>(f, nc, zb, t, pos, selfs, out, cnt, G, nbx);
    dim3 grid(nbx, N / 256);
    k_gram<<<grid, 256, 0, stream>>>((const unsigned short*)zb, t, pos, selfs, cnt, out, N);
}

// Round 12
// 108.096 us; speedup vs baseline: 1.9185x; 1.0059x over previous
//
#include <hip/hip_runtime.h>
#include <hip/hip_bf16.h>

typedef __attribute__((ext_vector_type(4))) float float4v;  // 4 fp32 acc
typedef __attribute__((ext_vector_type(2))) float floatx2;

// z is pre-scaled by sqrt(2*log2(e)), so MFMA dot = 2*log2(e)*cos and
// exp(2*cos) = exp2(dot) directly — no multiply in the epilogue.
#define ZSCALE 1.6986436f

#if __has_builtin(__builtin_amdgcn_exp2f)
#define VEXP2(x) __builtin_amdgcn_exp2f(x)   /* raw v_exp_f32; args in [-2.95,2.95] */
#else
#define VEXP2(x) exp2f(x)
#endif

// HW fp8 (OCP e4m3) pack/unpack — bit-identical to what the MFMA decodes.
__device__ __forceinline__ unsigned short pack_fp8pair(float x, float y){
    int p = __builtin_amdgcn_cvt_pk_fp8_f32(x, y, 0, 0);
    return (unsigned short)(p & 0xFFFF);
}
__device__ __forceinline__ floatx2 unpack_fp8pair(unsigned short u){
    return __builtin_amdgcn_cvt_pk_f32_fp8((int)u, 0);
}

// K1 (prep): one wave per group, 4 groups per block.
// Normalize rows (fp32 norm clamp 1e-8), scale ZSCALE, quantize to fp8 e4m3 (HW
// cvt), store packed (row = 128 B, k-order); zero t rows; pos/self from fp32 dots
// of the SAME fp8-dequantized z (consistent with MFMA sums). Fast path c==4.
// Group-0 wave also zeroes out[0] and the per-slab counters.
__global__ void k_prep(const float* __restrict__ f, const int* __restrict__ nc,
                       unsigned char* __restrict__ z8, float* __restrict__ t,
                       float* __restrict__ possum, float* __restrict__ selfs,
                       float* __restrict__ out, int* __restrict__ cnt,
                       int G, int nbx){
    int lane = threadIdx.x & 63;
    int g = blockIdx.x * 4 + (threadIdx.x >> 6);
    if (g >= G) return;
    if (g == 0){
        if (lane == 0) out[0] = 0.0f;
        for (int i = lane; i < nbx; i += 64) cnt[i] = 0;
    }
    int st = 0;
    {
        int i = lane;
        for (; i + 192 < g; i += 256)
            st += nc[i] + nc[i + 64] + nc[i + 128] + nc[i + 192];
        for (; i < g; i += 64) st += nc[i];
    }
    #pragma unroll
    for (int m = 1; m < 64; m <<= 1) st += __shfl_xor(st, m);
    int c = nc[g];
    for (int i = lane; i < c; i += 64) t[st + i] = 0.0f;

    if (c == 4){
        float2 v[4]; float ss[4];
        #pragma unroll
        for (int a = 0; a < 4; a++){
            v[a] = ((const float2*)(f + (size_t)(st + a) * 128))[lane];
            ss[a] = v[a].x * v[a].x + v[a].y * v[a].y;
        }
        #pragma unroll
        for (int m = 1; m < 64; m <<= 1){
            ss[0] += __shfl_xor(ss[0], m);
            ss[1] += __shfl_xor(ss[1], m);
            ss[2] += __shfl_xor(ss[2], m);
            ss[3] += __shfl_xor(ss[3], m);
        }
        float zx[4], zy[4];
        #pragma unroll
        for (int a = 0; a < 4; a++){
            float scale = ZSCALE / fmaxf(sqrtf(ss[a]), 1e-8f);
            unsigned short pk = pack_fp8pair(v[a].x * scale, v[a].y * scale);
            ((unsigned short*)(z8 + (size_t)(st + a) * 128))[lane] = pk;
            floatx2 d = unpack_fp8pair(pk);       // the SAME values k_gram sees
            zx[a] = d[0]; zy[a] = d[1];
        }
        float s[10];
        s[0] = zx[0]*zx[0] + zy[0]*zy[0];
        s[1] = zx[0]*zx[1] + zy[0]*zy[1];
        s[2] = zx[0]*zx[2] + zy[0]*zy[2];
        s[3] = zx[0]*zx[3] + zy[0]*zy[3];
        s[4] = zx[1]*zx[1] + zy[1]*zy[1];
        s[5] = zx[1]*zx[2] + zy[1]*zy[2];
        s[6] = zx[1]*zx[3] + zy[1]*zy[3];
        s[7] = zx[2]*zx[2] + zy[2]*zy[2];
        s[8] = zx[2]*zx[3] + zy[2]*zy[3];
        s[9] = zx[3]*zx[3] + zy[3]*zy[3];
        #pragma unroll
        for (int m = 1; m < 64; m <<= 1)
            #pragma unroll
            for (int u = 0; u < 10; u++) s[u] += __shfl_xor(s[u], m);
        if (lane == 0){
            float E0 = exp2f(s[0]), E1 = exp2f(s[1]), E2 = exp2f(s[2]), E3 = exp2f(s[3]);
            float E4 = exp2f(s[4]), E5 = exp2f(s[5]), E6 = exp2f(s[6]), E7 = exp2f(s[7]);
            float E8 = exp2f(s[8]), E9 = exp2f(s[9]);
            possum[st + 0] = E1 + E2 + E3;  selfs[st + 0] = E0;
            possum[st + 1] = E1 + E5 + E6;  selfs[st + 1] = E4;
            possum[st + 2] = E2 + E5 + E8;  selfs[st + 2] = E7;
            possum[st + 3] = E3 + E6 + E8;  selfs[st + 3] = E9;
        }
    } else {
        for (int r = 0; r < c; r++){
            const float2* fr = (const float2*)(f + (size_t)(st + r) * 128);
            float2 vv = fr[lane];
            float ss2 = vv.x * vv.x + vv.y * vv.y;
            #pragma unroll
            for (int m = 1; m < 64; m <<= 1) ss2 += __shfl_xor(ss2, m);
            float scale = ZSCALE / fmaxf(sqrtf(ss2), 1e-8f);
            ((unsigned short*)(z8 + (size_t)(st + r) * 128))[lane] =
                pack_fp8pair(vv.x * scale, vv.y * scale);
        }
        for (int a = 0; a < c; a++){
            floatx2 da = unpack_fp8pair(((unsigned short*)(z8 + (size_t)(st + a) * 128))[lane]);
            float pacc = 0.0f;
            for (int b = 0; b < c; b++){
                floatx2 db = unpack_fp8pair(((unsigned short*)(z8 + (size_t)(st + b) * 128))[lane]);
                float sdot = da[0] * db[0] + da[1] * db[1];
                #pragma unroll
                for (int m = 1; m < 64; m <<= 1) sdot += __shfl_xor(sdot, m);
                float e = exp2f(sdot);
                if (b == a){ if (lane == 0) selfs[st + a] = e; }
                else pacc += e;
            }
            if (lane == 0) possum[st + a] = pacc;
        }
    }
}

// K2: Gram row-sums, fp8 e4m3 MFMA (halved fragment bytes vs bf16 — attacks the
// modeled L1-line bottleneck). R5 geometry: 1024 blocks, wave = 64 rows x 256
// cols as 16 strips of 16 cols; VEXP2 epilogue; fused finalize via returning
// atomics (ack consumed -> RMW complete at coherence point before cnt bump; NO
// threadfence — R9 showed that costs 2x wall via L2 writeback). Device-scope
// atomics only (G16-safe).
// fp8 fragment: lane holds z8[base+(lane&15)][k = ki*32 + (lane>>4)*8 .. +7]
// (same lane->(row,k) mapping as the verified bf16 16x16x32 shape; 8 B/lane).
// C layout: col = lane&15, row_local = mi*16 + quad*4 + r.
__global__ __launch_bounds__(256) void k_gram(const unsigned char* __restrict__ z8,
                                              float* __restrict__ t,
                                              const float* __restrict__ possum,
                                              const float* __restrict__ selfs,
                                              int* __restrict__ cnt,
                                              float* __restrict__ out, int N){
    int tid  = threadIdx.x;
    int lane = tid & 63, w = tid >> 6;
    int quad = lane >> 4, l15 = lane & 15;
    int bx = blockIdx.x, nby = gridDim.y;
    int r0 = bx * 256 + w * 64;
    int c0 = blockIdx.y * 256;
    size_t lq = (size_t)l15 * 128 + quad * 8;   // byte offset within a 16-row group

    const unsigned char* za = z8 + (size_t)r0 * 128;
    long long af[4][4];
    #pragma unroll
    for (int mi = 0; mi < 4; mi++)
        #pragma unroll
        for (int ki = 0; ki < 4; ki++)
            af[mi][ki] = *(const long long*)(za + (size_t)(mi * 16) * 128 + lq + ki * 32);

    float ts[4][4];
    #pragma unroll
    for (int mi = 0; mi < 4; mi++)
        #pragma unroll
        for (int r = 0; r < 4; r++) ts[mi][r] = 0.0f;

    const unsigned char* zp = z8 + (size_t)c0 * 128 + lq;
    #pragma unroll 1
    for (int s = 0; s < 16; s++){
        long long b0 = *(const long long*)(zp);
        long long b1 = *(const long long*)(zp + 32);
        long long b2 = *(const long long*)(zp + 64);
        long long b3 = *(const long long*)(zp + 96);
        float4v acc[4];
        #pragma unroll
        for (int mi = 0; mi < 4; mi++) acc[mi] = (float4v){0.0f, 0.0f, 0.0f, 0.0f};
        #pragma unroll
        for (int mi = 0; mi < 4; mi++)
            acc[mi] = __builtin_amdgcn_mfma_f32_16x16x32_fp8_fp8(af[mi][0], b0, acc[mi], 0, 0, 0);
        #pragma unroll
        for (int mi = 0; mi < 4; mi++)
            acc[mi] = __builtin_amdgcn_mfma_f32_16x16x32_fp8_fp8(af[mi][1], b1, acc[mi], 0, 0, 0);
        #pragma unroll
        for (int mi = 0; mi < 4; mi++)
            acc[mi] = __builtin_amdgcn_mfma_f32_16x16x32_fp8_fp8(af[mi][2], b2, acc[mi], 0, 0, 0);
        #pragma unroll
        for (int mi = 0; mi < 4; mi++)
            acc[mi] = __builtin_amdgcn_mfma_f32_16x16x32_fp8_fp8(af[mi][3], b3, acc[mi], 0, 0, 0);
        #pragma unroll
        for (int mi = 0; mi < 4; mi++)
            #pragma unroll
            for (int r = 0; r < 4; r++)
                ts[mi][r] += VEXP2(acc[mi][r]);
        zp += 16 * 128;   // next 16-col strip (fp8 row = 128 B)
    }

    // reduce across the 16 column-lanes (same quad); returning atomics, ack consumed
    float ack = 0.0f;
    #pragma unroll
    for (int mi = 0; mi < 4; mi++)
        #pragma unroll
        for (int r = 0; r < 4; r++){
            float v = ts[mi][r];
            v += __shfl_xor(v, 1);
            v += __shfl_xor(v, 2);
            v += __shfl_xor(v, 4);
            v += __shfl_xor(v, 8);
            if (l15 == 0) ack += atomicAdd(&t[r0 + mi * 16 + quad * 4 + r], v);
        }
    if (ack == -1.0f) out[0] = 0.0f;   // never taken; keeps the returning form

    __syncthreads();   // all 4 waves' t-atomics acknowledged

    __shared__ int lastflag;
    if (tid == 0) lastflag = (atomicAdd(&cnt[bx], 1) == nby - 1);
    __syncthreads();
    if (lastflag){
        int r = bx * 256 + tid;     // 256 rows per slab, one per thread
        float s = 0.0f;
        if (r < N){
            float tv = atomicAdd(&t[r], 0.0f);   // coherent read of completed row sum
            float p  = possum[r];
            float nn = tv - p - selfs[r];
            s = logf(nn) - logf(p);
        }
        #pragma unroll
        for (int m = 1; m < 64; m <<= 1) s += __shfl_xor(s, m);
        __shared__ float red[4];
        if ((tid & 63) == 0) red[tid >> 6] = s;
        __syncthreads();
        if (tid == 0) atomicAdd(out, (red[0] + red[1] + red[2] + red[3]) / (float)N);
    }
}

extern "C" void kernel_launch(void* const* d_in, const int* in_sizes, int n_in,
                              void* d_out, int out_size, void* d_ws, size_t ws_size,
                              hipStream_t stream){
    const float* f  = (const float*)d_in[0];
    const int*   nc = (const int*)d_in[1];
    int N = in_sizes[0] / 128;   // 8192
    int G = in_sizes[1];         // 2048
    int nbx = N / 256;           // 32 row-slabs

    unsigned char* z8 = (unsigned char*)d_ws;                     // N*128 B fp8 z (pre-scaled)
    float* t     = (float*)((char*)d_ws + (size_t)N * 128);       // N fp32
    float* pos   = t + N;
    float* selfs = pos + N;
    int*   cnt   = (int*)(selfs + N);                             // nbx ints
    float* out   = (float*)d_out;

    k_prep<<<(G + 3) / 4, 256, 0, stream>>>(f, nc, z8, t, pos, selfs, out, cnt, G, nbx);
    dim3 grid(nbx, N / 256);
    k_gram<<<grid, 256, 0, stream>>>(z8, t, pos, selfs, cnt, out, N);
}

// Round 13
// 102.590 us; speedup vs baseline: 2.0214x; 1.0537x over previous
//
#include <hip/hip_runtime.h>
#include <hip/hip_bf16.h>

typedef __attribute__((ext_vector_type(4))) float float4v;  // 4 fp32 acc
typedef __attribute__((ext_vector_type(2))) float floatx2;

// z is pre-scaled by sqrt(2*log2(e)), so MFMA dot = 2*log2(e)*cos and
// exp(2*cos) = exp2(dot) directly — no multiply in the epilogue.
#define ZSCALE 1.6986436f

#if __has_builtin(__builtin_amdgcn_exp2f)
#define VEXP2(x) __builtin_amdgcn_exp2f(x)   /* raw v_exp_f32; args in [-2.95,2.95] */
#else
#define VEXP2(x) exp2f(x)
#endif

// HW fp8 (OCP e4m3) pack/unpack — bit-identical to what the MFMA decodes.
__device__ __forceinline__ unsigned short pack_fp8pair(float x, float y){
    int p = __builtin_amdgcn_cvt_pk_fp8_f32(x, y, 0, 0);
    return (unsigned short)(p & 0xFFFF);
}
__device__ __forceinline__ floatx2 unpack_fp8pair(unsigned short u){
    return __builtin_amdgcn_cvt_pk_f32_fp8((int)u, 0);
}

// K1 (prep): one wave per group, 4 groups per block.
// Normalize rows (fp32 norm clamp 1e-8), scale ZSCALE, quantize fp8 e4m3 (HW cvt),
// store packed (row = 128 B); zero t rows; pos/self from fp32 dots of the SAME
// fp8-dequantized z (consistent with MFMA sums). Fast path c==4.
// Group-0 wave also zeroes out[0] and the per-slab counters.
__global__ void k_prep(const float* __restrict__ f, const int* __restrict__ nc,
                       unsigned char* __restrict__ z8, float* __restrict__ t,
                       float* __restrict__ possum, float* __restrict__ selfs,
                       float* __restrict__ out, int* __restrict__ cnt,
                       int G, int nbx){
    int lane = threadIdx.x & 63;
    int g = blockIdx.x * 4 + (threadIdx.x >> 6);
    if (g >= G) return;
    if (g == 0){
        if (lane == 0) out[0] = 0.0f;
        for (int i = lane; i < nbx; i += 64) cnt[i] = 0;
    }
    int st = 0;
    {
        int i = lane;
        for (; i + 192 < g; i += 256)
            st += nc[i] + nc[i + 64] + nc[i + 128] + nc[i + 192];
        for (; i < g; i += 64) st += nc[i];
    }
    #pragma unroll
    for (int m = 1; m < 64; m <<= 1) st += __shfl_xor(st, m);
    int c = nc[g];
    for (int i = lane; i < c; i += 64) t[st + i] = 0.0f;

    if (c == 4){
        float2 v[4]; float ss[4];
        #pragma unroll
        for (int a = 0; a < 4; a++){
            v[a] = ((const float2*)(f + (size_t)(st + a) * 128))[lane];
            ss[a] = v[a].x * v[a].x + v[a].y * v[a].y;
        }
        #pragma unroll
        for (int m = 1; m < 64; m <<= 1){
            ss[0] += __shfl_xor(ss[0], m);
            ss[1] += __shfl_xor(ss[1], m);
            ss[2] += __shfl_xor(ss[2], m);
            ss[3] += __shfl_xor(ss[3], m);
        }
        float zx[4], zy[4];
        #pragma unroll
        for (int a = 0; a < 4; a++){
            float scale = ZSCALE / fmaxf(sqrtf(ss[a]), 1e-8f);
            unsigned short pk = pack_fp8pair(v[a].x * scale, v[a].y * scale);
            ((unsigned short*)(z8 + (size_t)(st + a) * 128))[lane] = pk;
            floatx2 d = unpack_fp8pair(pk);       // the SAME values k_gram sees
            zx[a] = d[0]; zy[a] = d[1];
        }
        float s[10];
        s[0] = zx[0]*zx[0] + zy[0]*zy[0];
        s[1] = zx[0]*zx[1] + zy[0]*zy[1];
        s[2] = zx[0]*zx[2] + zy[0]*zy[2];
        s[3] = zx[0]*zx[3] + zy[0]*zy[3];
        s[4] = zx[1]*zx[1] + zy[1]*zy[1];
        s[5] = zx[1]*zx[2] + zy[1]*zy[2];
        s[6] = zx[1]*zx[3] + zy[1]*zy[3];
        s[7] = zx[2]*zx[2] + zy[2]*zy[2];
        s[8] = zx[2]*zx[3] + zy[2]*zy[3];
        s[9] = zx[3]*zx[3] + zy[3]*zy[3];
        #pragma unroll
        for (int m = 1; m < 64; m <<= 1)
            #pragma unroll
            for (int u = 0; u < 10; u++) s[u] += __shfl_xor(s[u], m);
        if (lane == 0){
            float E0 = exp2f(s[0]), E1 = exp2f(s[1]), E2 = exp2f(s[2]), E3 = exp2f(s[3]);
            float E4 = exp2f(s[4]), E5 = exp2f(s[5]), E6 = exp2f(s[6]), E7 = exp2f(s[7]);
            float E8 = exp2f(s[8]), E9 = exp2f(s[9]);
            possum[st + 0] = E1 + E2 + E3;  selfs[st + 0] = E0;
            possum[st + 1] = E1 + E5 + E6;  selfs[st + 1] = E4;
            possum[st + 2] = E2 + E5 + E8;  selfs[st + 2] = E7;
            possum[st + 3] = E3 + E6 + E8;  selfs[st + 3] = E9;
        }
    } else {
        for (int r = 0; r < c; r++){
            const float2* fr = (const float2*)(f + (size_t)(st + r) * 128);
            float2 vv = fr[lane];
            float ss2 = vv.x * vv.x + vv.y * vv.y;
            #pragma unroll
            for (int m = 1; m < 64; m <<= 1) ss2 += __shfl_xor(ss2, m);
            float scale = ZSCALE / fmaxf(sqrtf(ss2), 1e-8f);
            ((unsigned short*)(z8 + (size_t)(st + r) * 128))[lane] =
                pack_fp8pair(vv.x * scale, vv.y * scale);
        }
        for (int a = 0; a < c; a++){
            floatx2 da = unpack_fp8pair(((unsigned short*)(z8 + (size_t)(st + a) * 128))[lane]);
            float pacc = 0.0f;
            for (int b = 0; b < c; b++){
                floatx2 db = unpack_fp8pair(((unsigned short*)(z8 + (size_t)(st + b) * 128))[lane]);
                float sdot = da[0] * db[0] + da[1] * db[1];
                #pragma unroll
                for (int m = 1; m < 64; m <<= 1) sdot += __shfl_xor(sdot, m);
                float e = exp2f(sdot);
                if (b == a){ if (lane == 0) selfs[st + a] = e; }
                else pacc += e;
            }
            if (lane == 0) possum[st + a] = pacc;
        }
    }
}

// K2: Gram row-sums — composition of every measured-best piece:
//  * 512-block geometry (best across R1-R12: 44.1 µs): grid (32 slabs, 16 col-
//    chunks); wave = 64 rows x 512 cols as 32 strips of 16. Longest-lived blocks
//    amortize per-block fixed costs (A-gather, launch, drain) best.
//  * fp8 e4m3 MFMA: half the fragment bytes (FETCH halved, R12-verified).
//  * VEXP2 epilogue: 1 v_exp + 1 v_add per element (halves VALUBusy, R10-verified).
//  * fused finalize via returning atomics (no threadfence — R9 showed the L2
//    writeback costs 2x; ack-consumption orders the RMWs, R11/R12-verified).
// Device-scope atomics only — no dispatch-order/co-residency assumptions.
// fp8 fragment: lane holds z8[base+(lane&15)][k = ki*32 + (lane>>4)*8 .. +7]
// C layout: col = lane&15, row_local = mi*16 + quad*4 + r.
__global__ __launch_bounds__(256) void k_gram(const unsigned char* __restrict__ z8,
                                              float* __restrict__ t,
                                              const float* __restrict__ possum,
                                              const float* __restrict__ selfs,
                                              int* __restrict__ cnt,
                                              float* __restrict__ out, int N){
    int tid  = threadIdx.x;
    int lane = tid & 63, w = tid >> 6;
    int quad = lane >> 4, l15 = lane & 15;
    int bx = blockIdx.x, nby = gridDim.y;
    int r0 = bx * 256 + w * 64;
    int c0 = blockIdx.y * 512;
    size_t lq = (size_t)l15 * 128 + quad * 8;   // byte offset within a 16-row group

    const unsigned char* za = z8 + (size_t)r0 * 128;
    long long af[4][4];
    #pragma unroll
    for (int mi = 0; mi < 4; mi++)
        #pragma unroll
        for (int ki = 0; ki < 4; ki++)
            af[mi][ki] = *(const long long*)(za + (size_t)(mi * 16) * 128 + lq + ki * 32);

    float ts[4][4];
    #pragma unroll
    for (int mi = 0; mi < 4; mi++)
        #pragma unroll
        for (int r = 0; r < 4; r++) ts[mi][r] = 0.0f;

    const unsigned char* zp = z8 + (size_t)c0 * 128 + lq;
    #pragma unroll 1
    for (int s = 0; s < 32; s++){
        long long b0 = *(const long long*)(zp);
        long long b1 = *(const long long*)(zp + 32);
        long long b2 = *(const long long*)(zp + 64);
        long long b3 = *(const long long*)(zp + 96);
        float4v acc[4];
        #pragma unroll
        for (int mi = 0; mi < 4; mi++) acc[mi] = (float4v){0.0f, 0.0f, 0.0f, 0.0f};
        #pragma unroll
        for (int mi = 0; mi < 4; mi++)
            acc[mi] = __builtin_amdgcn_mfma_f32_16x16x32_fp8_fp8(af[mi][0], b0, acc[mi], 0, 0, 0);
        #pragma unroll
        for (int mi = 0; mi < 4; mi++)
            acc[mi] = __builtin_amdgcn_mfma_f32_16x16x32_fp8_fp8(af[mi][1], b1, acc[mi], 0, 0, 0);
        #pragma unroll
        for (int mi = 0; mi < 4; mi++)
            acc[mi] = __builtin_amdgcn_mfma_f32_16x16x32_fp8_fp8(af[mi][2], b2, acc[mi], 0, 0, 0);
        #pragma unroll
        for (int mi = 0; mi < 4; mi++)
            acc[mi] = __builtin_amdgcn_mfma_f32_16x16x32_fp8_fp8(af[mi][3], b3, acc[mi], 0, 0, 0);
        #pragma unroll
        for (int mi = 0; mi < 4; mi++)
            #pragma unroll
            for (int r = 0; r < 4; r++)
                ts[mi][r] += VEXP2(acc[mi][r]);
        zp += 16 * 128;   // next 16-col strip (fp8 row = 128 B)
    }

    // reduce across the 16 column-lanes (same quad); returning atomics, ack consumed
    float ack = 0.0f;
    #pragma unroll
    for (int mi = 0; mi < 4; mi++)
        #pragma unroll
        for (int r = 0; r < 4; r++){
            float v = ts[mi][r];
            v += __shfl_xor(v, 1);
            v += __shfl_xor(v, 2);
            v += __shfl_xor(v, 4);
            v += __shfl_xor(v, 8);
            if (l15 == 0) ack += atomicAdd(&t[r0 + mi * 16 + quad * 4 + r], v);
        }
    if (ack == -1.0f) out[0] = 0.0f;   // never taken; keeps the returning form

    __syncthreads();   // all 4 waves' t-atomics acknowledged

    __shared__ int lastflag;
    if (tid == 0) lastflag = (atomicAdd(&cnt[bx], 1) == nby - 1);
    __syncthreads();
    if (lastflag){
        int r = bx * 256 + tid;     // 256 rows per slab, one per thread
        float s = 0.0f;
        if (r < N){
            float tv = atomicAdd(&t[r], 0.0f);   // coherent read of completed row sum
            float p  = possum[r];
            float nn = tv - p - selfs[r];
            s = logf(nn) - logf(p);
        }
        #pragma unroll
        for (int m = 1; m < 64; m <<= 1) s += __shfl_xor(s, m);
        __shared__ float red[4];
        if ((tid & 63) == 0) red[tid >> 6] = s;
        __syncthreads();
        if (tid == 0) atomicAdd(out, (red[0] + red[1] + red[2] + red[3]) / (float)N);
    }
}

extern "C" void kernel_launch(void* const* d_in, const int* in_sizes, int n_in,
                              void* d_out, int out_size, void* d_ws, size_t ws_size,
                              hipStream_t stream){
    const float* f  = (const float*)d_in[0];
    const int*   nc = (const int*)d_in[1];
    int N = in_sizes[0] / 128;   // 8192
    int G = in_sizes[1];         // 2048
    int nbx = N / 256;           // 32 row-slabs

    unsigned char* z8 = (unsigned char*)d_ws;                     // N*128 B fp8 z (pre-scaled)
    float* t     = (float*)((char*)d_ws + (size_t)N * 128);       // N fp32
    float* pos   = t + N;
    float* selfs = pos + N;
    int*   cnt   = (int*)(selfs + N);                             // nbx ints
    float* out   = (float*)d_out;

    k_prep<<<(G + 3) / 4, 256, 0, stream>>>(f, nc, z8, t, pos, selfs, out, cnt, G, nbx);
    dim3 grid(nbx, N / 512);
    k_gram<<<grid, 256, 0, stream>>>(z8, t, pos, selfs, cnt, out, N);
}

// Round 14
// 88.956 us; speedup vs baseline: 2.3312x; 1.1533x over previous
//
#include <hip/hip_runtime.h>
#include <hip/hip_bf16.h>

typedef __attribute__((ext_vector_type(4))) float float4v;  // 4 fp32 acc
typedef __attribute__((ext_vector_type(2))) float floatx2;
typedef __attribute__((ext_vector_type(8))) int v8i;        // 32 B MX fragment

// z is pre-scaled by sqrt(2*log2(e)), so MFMA dot = 2*log2(e)*cos and
// exp(2*cos) = exp2(dot) directly — no multiply in the epilogue.
#define ZSCALE 1.6986436f
#define SCALE_ONE 127u   /* E8M0 biased exponent for 1.0 */

#if __has_builtin(__builtin_amdgcn_exp2f)
#define VEXP2(x) __builtin_amdgcn_exp2f(x)   /* raw v_exp_f32; args in [-2.95,2.95] */
#else
#define VEXP2(x) exp2f(x)
#endif

// HW fp8 (OCP e4m3) pack/unpack — bit-identical to what the MFMA decodes.
__device__ __forceinline__ unsigned short pack_fp8pair(float x, float y){
    int p = __builtin_amdgcn_cvt_pk_fp8_f32(x, y, 0, 0);
    return (unsigned short)(p & 0xFFFF);
}
__device__ __forceinline__ floatx2 unpack_fp8pair(unsigned short u){
    return __builtin_amdgcn_cvt_pk_f32_fp8((int)u, 0);
}

// K1 (prep): one wave per group, 4 groups per block.  (unchanged from R13)
__global__ void k_prep(const float* __restrict__ f, const int* __restrict__ nc,
                       unsigned char* __restrict__ z8, float* __restrict__ t,
                       float* __restrict__ possum, float* __restrict__ selfs,
                       float* __restrict__ out, int* __restrict__ cnt,
                       int G, int nbx){
    int lane = threadIdx.x & 63;
    int g = blockIdx.x * 4 + (threadIdx.x >> 6);
    if (g >= G) return;
    if (g == 0){
        if (lane == 0) out[0] = 0.0f;
        for (int i = lane; i < nbx; i += 64) cnt[i] = 0;
    }
    int st = 0;
    {
        int i = lane;
        for (; i + 192 < g; i += 256)
            st += nc[i] + nc[i + 64] + nc[i + 128] + nc[i + 192];
        for (; i < g; i += 64) st += nc[i];
    }
    #pragma unroll
    for (int m = 1; m < 64; m <<= 1) st += __shfl_xor(st, m);
    int c = nc[g];
    for (int i = lane; i < c; i += 64) t[st + i] = 0.0f;

    if (c == 4){
        float2 v[4]; float ss[4];
        #pragma unroll
        for (int a = 0; a < 4; a++){
            v[a] = ((const float2*)(f + (size_t)(st + a) * 128))[lane];
            ss[a] = v[a].x * v[a].x + v[a].y * v[a].y;
        }
        #pragma unroll
        for (int m = 1; m < 64; m <<= 1){
            ss[0] += __shfl_xor(ss[0], m);
            ss[1] += __shfl_xor(ss[1], m);
            ss[2] += __shfl_xor(ss[2], m);
            ss[3] += __shfl_xor(ss[3], m);
        }
        float zx[4], zy[4];
        #pragma unroll
        for (int a = 0; a < 4; a++){
            float scale = ZSCALE / fmaxf(sqrtf(ss[a]), 1e-8f);
            unsigned short pk = pack_fp8pair(v[a].x * scale, v[a].y * scale);
            ((unsigned short*)(z8 + (size_t)(st + a) * 128))[lane] = pk;
            floatx2 d = unpack_fp8pair(pk);       // the SAME values k_gram sees
            zx[a] = d[0]; zy[a] = d[1];
        }
        float s[10];
        s[0] = zx[0]*zx[0] + zy[0]*zy[0];
        s[1] = zx[0]*zx[1] + zy[0]*zy[1];
        s[2] = zx[0]*zx[2] + zy[0]*zy[2];
        s[3] = zx[0]*zx[3] + zy[0]*zy[3];
        s[4] = zx[1]*zx[1] + zy[1]*zy[1];
        s[5] = zx[1]*zx[2] + zy[1]*zy[2];
        s[6] = zx[1]*zx[3] + zy[1]*zy[3];
        s[7] = zx[2]*zx[2] + zy[2]*zy[2];
        s[8] = zx[2]*zx[3] + zy[2]*zy[3];
        s[9] = zx[3]*zx[3] + zy[3]*zy[3];
        #pragma unroll
        for (int m = 1; m < 64; m <<= 1)
            #pragma unroll
            for (int u = 0; u < 10; u++) s[u] += __shfl_xor(s[u], m);
        if (lane == 0){
            float E0 = exp2f(s[0]), E1 = exp2f(s[1]), E2 = exp2f(s[2]), E3 = exp2f(s[3]);
            float E4 = exp2f(s[4]), E5 = exp2f(s[5]), E6 = exp2f(s[6]), E7 = exp2f(s[7]);
            float E8 = exp2f(s[8]), E9 = exp2f(s[9]);
            possum[st + 0] = E1 + E2 + E3;  selfs[st + 0] = E0;
            possum[st + 1] = E1 + E5 + E6;  selfs[st + 1] = E4;
            possum[st + 2] = E2 + E5 + E8;  selfs[st + 2] = E7;
            possum[st + 3] = E3 + E6 + E8;  selfs[st + 3] = E9;
        }
    } else {
        for (int r = 0; r < c; r++){
            const float2* fr = (const float2*)(f + (size_t)(st + r) * 128);
            float2 vv = fr[lane];
            float ss2 = vv.x * vv.x + vv.y * vv.y;
            #pragma unroll
            for (int m = 1; m < 64; m <<= 1) ss2 += __shfl_xor(ss2, m);
            float scale = ZSCALE / fmaxf(sqrtf(ss2), 1e-8f);
            ((unsigned short*)(z8 + (size_t)(st + r) * 128))[lane] =
                pack_fp8pair(vv.x * scale, vv.y * scale);
        }
        for (int a = 0; a < c; a++){
            floatx2 da = unpack_fp8pair(((unsigned short*)(z8 + (size_t)(st + a) * 128))[lane]);
            float pacc = 0.0f;
            for (int b = 0; b < c; b++){
                floatx2 db = unpack_fp8pair(((unsigned short*)(z8 + (size_t)(st + b) * 128))[lane]);
                float sdot = da[0] * db[0] + da[1] * db[1];
                #pragma unroll
                for (int m = 1; m < 64; m <<= 1) sdot += __shfl_xor(sdot, m);
                float e = exp2f(sdot);
                if (b == a){ if (lane == 0) selfs[st + a] = e; }
                else pacc += e;
            }
            if (lane == 0) possum[st + a] = pacc;
        }
    }
}

// K2: Gram row-sums — R13 structure with the K-loop collapsed into ONE
// MX-scaled MFMA (v_mfma_scale_f32_16x16x128_f8f6f4, scale=1.0 -> bit-identical
// to non-scaled fp8). MFMA count drops 16x per strip (4 instead of 16 K=32 ops):
// the dominant pipe term (~20k cyc/SIMD, 55% of R13's wall) drops to ~9k.
// A/B fragment layout risk is ZERO for a self-Gram: any HW k-permutation applies
// identically to both operands (loaded with the same per-lane pattern from the
// same z8) and cancels in sum_k A[m][k]B[n][k]. C/D layout is shape-determined
// (verified): col = lane&15, row_local = mi*16 + quad*4 + r.
// Geometry (best measured): 512 blocks — grid (32 slabs, 16 col-chunks), wave =
// 64 rows x 512 cols as 32 strips of 16. Fused finalize via returning atomics
// (no threadfence — R9: L2 writeback costs 2x). Device-scope atomics only.
// MX fragment: lane holds z8[base + (lane&15)][bytes (lane>>4)*32 .. +31] (32 B).
__global__ __launch_bounds__(256) void k_gram(const unsigned char* __restrict__ z8,
                                              float* __restrict__ t,
                                              const float* __restrict__ possum,
                                              const float* __restrict__ selfs,
                                              int* __restrict__ cnt,
                                              float* __restrict__ out, int N){
    int tid  = threadIdx.x;
    int lane = tid & 63, w = tid >> 6;
    int quad = lane >> 4, l15 = lane & 15;
    int bx = blockIdx.x, nby = gridDim.y;
    int r0 = bx * 256 + w * 64;
    int c0 = blockIdx.y * 512;
    size_t lq = (size_t)l15 * 128 + quad * 32;   // 32-B per-lane MX fragment offset

    const unsigned char* za = z8 + (size_t)r0 * 128;
    v8i af[4];
    #pragma unroll
    for (int mi = 0; mi < 4; mi++)
        af[mi] = *(const v8i*)(za + (size_t)(mi * 16) * 128 + lq);

    float ts[4][4];
    #pragma unroll
    for (int mi = 0; mi < 4; mi++)
        #pragma unroll
        for (int r = 0; r < 4; r++) ts[mi][r] = 0.0f;

    const unsigned char* zp = z8 + (size_t)c0 * 128 + lq;
    #pragma unroll 1
    for (int s = 0; s < 32; s++){
        v8i bf = *(const v8i*)(zp);
        float4v acc[4];
        #pragma unroll
        for (int mi = 0; mi < 4; mi++) acc[mi] = (float4v){0.0f, 0.0f, 0.0f, 0.0f};
        #pragma unroll
        for (int mi = 0; mi < 4; mi++)
            acc[mi] = __builtin_amdgcn_mfma_scale_f32_16x16x128_f8f6f4(
                af[mi], bf, acc[mi], 0, 0, 0, SCALE_ONE, 0, SCALE_ONE);
        #pragma unroll
        for (int mi = 0; mi < 4; mi++)
            #pragma unroll
            for (int r = 0; r < 4; r++)
                ts[mi][r] += VEXP2(acc[mi][r]);
        zp += 16 * 128;   // next 16-col strip (fp8 row = 128 B)
    }

    // reduce across the 16 column-lanes (same quad); returning atomics, ack consumed
    float ack = 0.0f;
    #pragma unroll
    for (int mi = 0; mi < 4; mi++)
        #pragma unroll
        for (int r = 0; r < 4; r++){
            float v = ts[mi][r];
            v += __shfl_xor(v, 1);
            v += __shfl_xor(v, 2);
            v += __shfl_xor(v, 4);
            v += __shfl_xor(v, 8);
            if (l15 == 0) ack += atomicAdd(&t[r0 + mi * 16 + quad * 4 + r], v);
        }
    if (ack == -1.0f) out[0] = 0.0f;   // never taken; keeps the returning form

    __syncthreads();   // all 4 waves' t-atomics acknowledged

    __shared__ int lastflag;
    if (tid == 0) lastflag = (atomicAdd(&cnt[bx], 1) == nby - 1);
    __syncthreads();
    if (lastflag){
        int r = bx * 256 + tid;     // 256 rows per slab, one per thread
        float s = 0.0f;
        if (r < N){
            float tv = atomicAdd(&t[r], 0.0f);   // coherent read of completed row sum
            float p  = possum[r];
            float nn = tv - p - selfs[r];
            s = logf(nn) - logf(p);
        }
        #pragma unroll
        for (int m = 1; m < 64; m <<= 1) s += __shfl_xor(s, m);
        __shared__ float red[4];
        if ((tid & 63) == 0) red[tid >> 6] = s;
        __syncthreads();
        if (tid == 0) atomicAdd(out, (red[0] + red[1] + red[2] + red[3]) / (float)N);
    }
}

extern "C" void kernel_launch(void* const* d_in, const int* in_sizes, int n_in,
                              void* d_out, int out_size, void* d_ws, size_t ws_size,
                              hipStream_t stream){
    const float* f  = (const float*)d_in[0];
    const int*   nc = (const int*)d_in[1];
    int N = in_sizes[0] / 128;   // 8192
    int G = in_sizes[1];         // 2048
    int nbx = N / 256;           // 32 row-slabs

    unsigned char* z8 = (unsigned char*)d_ws;                     // N*128 B fp8 z (pre-scaled)
    float* t     = (float*)((char*)d_ws + (size_t)N * 128);       // N fp32
    float* pos   = t + N;
    float* selfs = pos + N;
    int*   cnt   = (int*)(selfs + N);                             // nbx ints
    float* out   = (float*)d_out;

    k_prep<<<(G + 3) / 4, 256, 0, stream>>>(f, nc, z8, t, pos, selfs, out, cnt, G, nbx);
    dim3 grid(nbx, N / 512);
    k_gram<<<grid, 256, 0, stream>>>(z8, t, pos, selfs, cnt, out, N);
}